// Round 2
// baseline (1893.823 us; speedup 1.0000x reference)
//
#include <hip/hip_runtime.h>
#include <math.h>
#include <stdint.h>

// ---------------- constants ----------------
#define B_ 4
#define T_ 1024
#define D_ 2048
#define H_ 32
#define N_ 64
static constexpr size_t BTD = (size_t)B_ * T_ * D_;   // 8388608

typedef __attribute__((ext_vector_type(8))) short short8;
typedef __attribute__((ext_vector_type(4))) float floatx4;

typedef __attribute__((address_space(3))) unsigned int       lds_u32;
typedef __attribute__((address_space(1))) const unsigned int glb_u32;

__device__ __forceinline__ void async_cp16(const unsigned short* g, unsigned short* l) {
  __builtin_amdgcn_global_load_lds((glb_u32*)g, (lds_u32*)l, 16, 0, 0);
}

__device__ __forceinline__ unsigned short f2bf(float f) {
  union { float f; unsigned int u; } v; v.f = f;
  unsigned int r = v.u + 0x7fffu + ((v.u >> 16) & 1u);
  return (unsigned short)(r >> 16);
}

__device__ __forceinline__ float bf2f(unsigned short u) {
  union { unsigned int u; float f; } v; v.u = (unsigned int)u << 16;
  return v.f;
}

__device__ __forceinline__ void store_bf4(unsigned short* dst, float a, float b, float c, float d) {
  unsigned long long v = (unsigned long long)f2bf(a) | ((unsigned long long)f2bf(b) << 16)
                       | ((unsigned long long)f2bf(c) << 32) | ((unsigned long long)f2bf(d) << 48);
  *(unsigned long long*)dst = v;
}

// load 8 bf16 (16B) -> 8 fp32
__device__ __forceinline__ void ld_bf8(const unsigned short* p, float* o) {
  union { short8 v; unsigned short u[8]; } t;
  t.v = *(const short8*)p;
#pragma unroll
  for (int c = 0; c < 8; ++c) o[c] = bf2f(t.u[c]);
}

__device__ __forceinline__ float sigm(float z) { return 1.f / (1.f + expf(-z)); }

// ---------------- token-shift mix: out_bf16 = x + (shift(x)-x)*coef ----------------
__global__ __launch_bounds__(256)
void mix_kernel(const float* __restrict__ x, const float* __restrict__ xprev,
                const float* __restrict__ coef, unsigned short* __restrict__ out)
{
  size_t i4 = (size_t)blockIdx.x * 256 + threadIdx.x;
  size_t e = i4 * 4;
  if (e >= BTD) return;
  int d = (int)(e & (D_ - 1));
  size_t bt = e >> 11;          // b*T + t
  int t = (int)(bt & (T_ - 1));
  float4 xv = *(const float4*)(x + e);
  float4 xs;
  if (t == 0) xs = *(const float4*)(xprev + ((bt >> 10) << 11) + d);
  else        xs = *(const float4*)(x + e - D_);
  float4 cf = *(const float4*)(coef + d);
  float o0 = xv.x + (xs.x - xv.x) * cf.x;
  float o1 = xv.y + (xs.y - xv.y) * cf.y;
  float o2 = xv.z + (xs.z - xv.z) * cf.z;
  float o3 = xv.w + (xs.w - xv.w) * cf.w;
  store_bf4(out + e, o0, o1, o2, o3);
}

// ---------------- transpose fp32 [R][C] -> bf16 [Cout][R], zero-pad c>=C ----------------
__global__ __launch_bounds__(256)
void transpose_bf16(const float* sA, const float* sB, const float* sC, const float* sD,
                    unsigned short* dA, unsigned short* dB, unsigned short* dC, unsigned short* dD,
                    int R, int C, int Cout)
{
  const float* src = blockIdx.z == 0 ? sA : blockIdx.z == 1 ? sB : blockIdx.z == 2 ? sC : sD;
  unsigned short* dst = blockIdx.z == 0 ? dA : blockIdx.z == 1 ? dB : blockIdx.z == 2 ? dC : dD;
  __shared__ float tile[64][65];
  int rBase = blockIdx.x * 64;
  int cBase = blockIdx.y * 64;
  int tid = threadIdx.x;
  int tc = tid & 63, tr4 = tid >> 6;
#pragma unroll
  for (int jj = 0; jj < 16; ++jj) {
    int r = rBase + jj * 4 + tr4;
    int c = cBase + tc;
    float v = (r < R && c < C) ? src[(size_t)r * C + c] : 0.f;
    tile[jj * 4 + tr4][tc] = v;
  }
  __syncthreads();
#pragma unroll
  for (int jj = 0; jj < 16; ++jj) {
    int cl = jj * 4 + tr4;
    int rl = tc;
    int c = cBase + cl, r = rBase + rl;
    if (c < Cout && r < R)
      dst[(size_t)c * R + r] = f2bf(tile[rl][cl]);
  }
}

// ---------------- bf16 MFMA GEMM: C[M,N] = A[M,K] @ BT[N,K]^T, fused epilogues ----------------
// EPI 0: fp32 raw              1: bf16 tanh     2: bf16 sigmoid    3: bf16 raw
// EPI 6: bf16 sigmoid(bias+v)  7: bf16 exp(-0.606531*sigmoid(bias+v))
template<int EPI>
__global__ __launch_bounds__(256, 2)
void gemm_bt(const unsigned short* __restrict__ A, const unsigned short* __restrict__ BT,
             float* __restrict__ Cf, unsigned short* __restrict__ Cb,
             int K, int ldc, int Nout, const float* __restrict__ bias)
{
  __shared__ unsigned short lA[128 * 32];
  __shared__ unsigned short lB[128 * 32];
  int tid = threadIdx.x;
  int lane = tid & 63;
  int wv = tid >> 6;
  int wrow = wv >> 1, wcol = wv & 1;
  int mBase = blockIdx.x * 128;
  int nBase = blockIdx.y * 128;
  int r16 = lane & 15, q = lane >> 4;

  floatx4 acc[4][4];
  floatx4 zero = {0.f, 0.f, 0.f, 0.f};
#pragma unroll
  for (int i = 0; i < 4; i++)
#pragma unroll
    for (int j = 0; j < 4; j++) acc[i][j] = zero;

  int arow = tid >> 2, ach = (tid & 3) * 8;
  const unsigned short* ga0 = A  + (size_t)(mBase + arow) * K + ach;
  const unsigned short* ga1 = A  + (size_t)(mBase + 64 + arow) * K + ach;
  const unsigned short* gb0 = BT + (size_t)(nBase + arow) * K + ach;
  const unsigned short* gb1 = BT + (size_t)(nBase + 64 + arow) * K + ach;
  unsigned short* la0 = lA + tid * 8;
  unsigned short* la1 = lA + 2048 + tid * 8;
  unsigned short* lb0 = lB + tid * 8;
  unsigned short* lb1 = lB + 2048 + tid * 8;

  for (int kb = 0; kb < K; kb += 32) {
    async_cp16(ga0 + kb, la0);
    async_cp16(ga1 + kb, la1);
    async_cp16(gb0 + kb, lb0);
    async_cp16(gb1 + kb, lb1);
    __syncthreads();
    short8 af[4], bf[4];
#pragma unroll
    for (int i = 0; i < 4; i++)
      af[i] = *(const short8*)(lA + (wrow * 64 + i * 16 + r16) * 32 + q * 8);
#pragma unroll
    for (int j = 0; j < 4; j++)
      bf[j] = *(const short8*)(lB + (wcol * 64 + j * 16 + r16) * 32 + q * 8);
#pragma unroll
    for (int i = 0; i < 4; i++)
#pragma unroll
      for (int j = 0; j < 4; j++)
        acc[i][j] = __builtin_amdgcn_mfma_f32_16x16x32_bf16(af[i], bf[j], acc[i][j], 0, 0, 0);
    __syncthreads();
  }

#pragma unroll
  for (int i = 0; i < 4; i++) {
    int r0 = mBase + wrow * 64 + i * 16 + q * 4;
#pragma unroll
    for (int j = 0; j < 4; j++) {
      int c = nBase + wcol * 64 + j * 16 + r16;
#pragma unroll
      for (int rg = 0; rg < 4; rg++) {
        float v = acc[i][j][rg];
        size_t idx = (size_t)(r0 + rg) * ldc + c;
        if (EPI == 0) {
          Cf[idx] = v;
        } else if (EPI == 1) {
          if (c < Nout) Cb[idx] = f2bf(tanhf(v));
        } else if (EPI == 2) {
          if (c < Nout) Cb[idx] = f2bf(sigm(v));
        } else if (EPI == 3) {
          if (c < Nout) Cb[idx] = f2bf(v);
        } else if (EPI == 6) {
          Cb[idx] = f2bf(sigm(bias[c] + v));
        } else if (EPI == 7) {
          Cb[idx] = f2bf(expf(-0.606531f * sigm(bias[c] + v)));
        }
      }
    }
  }
}

// ---------------- prep: kk norm, k/v finalize, aa/bb (in place, bf16) ----------------
__global__ __launch_bounds__(256)
void prep_kernel(unsigned short* __restrict__ kb, unsigned short* __restrict__ ab,
                 float* __restrict__ vb, unsigned short* __restrict__ vmb,
                 const float* __restrict__ vfirst, const float* __restrict__ kkc,
                 const float* __restrict__ kac, const int* __restrict__ layer)
{
  int g = blockIdx.x * 4 + (threadIdx.x >> 6);  // (b*T+t)*H + h
  int n = threadIdx.x & 63;
  size_t idx = (size_t)g * 64 + n;
  int d = ((g & (H_ - 1)) << 6) + n;
  float kr = bf2f(kb[idx]);
  float av = bf2f(ab[idx]);
  float vr = vb[idx];
  float vm = bf2f(vmb[idx]);
  float vf = vfirst[idx];
  float kkv = kr * kkc[d];
  float ss = kkv * kkv;
#pragma unroll
  for (int m = 1; m < 64; m <<= 1) ss += __shfl_xor(ss, m);
  float nrm = fmaxf(sqrtf(ss), 1e-12f);
  kkv = kkv / nrm;
  float kf = kr * (1.f + (av - 1.f) * kac[d]);
  float vfin = (*layer == 0) ? vr : vr + (vf - vr) * vm;
  kb[idx] = f2bf(kf);
  vb[idx] = vfin;
  ab[idx] = f2bf(-kkv);          // aa
  vmb[idx] = f2bf(kkv * av);     // bb
}

// ---------------- sequential scan: rows independent, 8 lanes/row ----------------
__global__ __launch_bounds__(256)
void scan_kernel(const unsigned short* __restrict__ rb, const unsigned short* __restrict__ wb,
                 const unsigned short* __restrict__ kb, const float* __restrict__ vb,
                 const unsigned short* __restrict__ ab, const unsigned short* __restrict__ bbv,
                 const float* __restrict__ s0, float* __restrict__ yb,
                 float* __restrict__ sf)
{
  int blk = blockIdx.x;        // 0..255
  int bh = blk >> 1;           // b*H + h
  int half = blk & 1;
  int b = bh >> 5, h = bh & 31;
  int tid = threadIdx.x;
  int lane = tid & 63;
  int wv = tid >> 6;
  int i = half * 32 + wv * 8 + (lane >> 3);
  int p = lane & 7;
  float st[8];
  {
    const float* sp = s0 + ((size_t)bh * 64 + i) * 64 + p * 8;
#pragma unroll
    for (int c = 0; c < 8; ++c) st[c] = sp[c];
  }
  size_t base = (size_t)b * T_ * D_ + h * 64;
  int co = p * 8;
  const unsigned short* pr = rb + base + co;
  const unsigned short* pw = wb + base + co;
  const unsigned short* pk = kb + base + co;
  const unsigned short* pa = ab + base + co;
  const unsigned short* pb = bbv + base + co;
  const float* pv = vb + base + i;
  float* py = yb + base + i;

#pragma unroll 2
  for (int t = 0; t < T_; ++t) {
    size_t o = (size_t)t * D_;
    float av[8], wvv[8], kv[8], bv[8], rv[8];
    ld_bf8(pa + o, av);
    ld_bf8(pw + o, wvv);
    ld_bf8(pk + o, kv);
    ld_bf8(pb + o, bv);
    ld_bf8(pr + o, rv);
    float vi = pv[o];

    float sa = 0.f;
#pragma unroll
    for (int c = 0; c < 8; ++c) sa = fmaf(st[c], av[c], sa);
    sa += __shfl_xor(sa, 1);
    sa += __shfl_xor(sa, 2);
    sa += __shfl_xor(sa, 4);

#pragma unroll
    for (int c = 0; c < 8; ++c) {
      float t0 = fmaf(vi, kv[c], sa * bv[c]);
      st[c] = fmaf(st[c], wvv[c], t0);
    }

    float y = 0.f;
#pragma unroll
    for (int c = 0; c < 8; ++c) y = fmaf(st[c], rv[c], y);
    y += __shfl_xor(y, 1);
    y += __shfl_xor(y, 2);
    y += __shfl_xor(y, 4);
    if (p == 0) py[o] = y;
  }

  float* sp = sf + ((size_t)bh * 64 + i) * 64 + p * 8;
#pragma unroll
  for (int c = 0; c < 8; ++c) sp[c] = st[c];
}

// ---------------- group-norm stats per (b,h) over (T,N) ----------------
__global__ __launch_bounds__(256)
void gn_stats(const float* __restrict__ yb, float* __restrict__ gn)
{
  int bh = blockIdx.x;
  int b = bh >> 5, h = bh & 31;
  int tid = threadIdx.x;
  int lane = tid & 63, wv = tid >> 6;
  size_t base = (size_t)b * T_ * D_ + h * 64;
  int n = tid & 63, t0 = tid >> 6;
  float s = 0.f, s2 = 0.f;
  for (int t = t0; t < T_; t += 4) {
    float v = yb[base + (size_t)t * D_ + n];
    s += v; s2 += v * v;
  }
#pragma unroll
  for (int m = 1; m < 64; m <<= 1) { s += __shfl_xor(s, m); s2 += __shfl_xor(s2, m); }
  __shared__ float ls[4], ls2[4];
  if (lane == 0) { ls[wv] = s; ls2[wv] = s2; }
  __syncthreads();
  if (tid == 0) {
    float S = ls[0] + ls[1] + ls[2] + ls[3];
    float S2 = ls2[0] + ls2[1] + ls2[2] + ls2[3];
    float mean = S * (1.f / 65536.f);
    float var = S2 * (1.f / 65536.f) - mean * mean;
    gn[2 * bh] = mean;
    gn[2 * bh + 1] = rsqrtf(var + 0.00064f);
  }
}

// ---------------- final A build: ((gn(y) + bonus)*g) -> bf16 ----------------
__global__ __launch_bounds__(256)
void final_mix(const float* __restrict__ yb, const float* __restrict__ gn,
               const unsigned short* __restrict__ rb, const unsigned short* __restrict__ kb,
               const float* __restrict__ vb, const unsigned short* __restrict__ gb,
               const float* __restrict__ lnw, const float* __restrict__ lnb,
               const float* __restrict__ rk, unsigned short* __restrict__ af)
{
  int bt = blockIdx.x;
  int b = bt >> 10;
  size_t base = (size_t)bt * D_;
  int tid = threadIdx.x;
  int d0 = tid * 8;

  float rr[8], kv[8], qv[8];
  ld_bf8(rb + base + d0, rr);
  ld_bf8(kb + base + d0, kv);
  *(float4*)&qv[0] = *(const float4*)(rk + d0);
  *(float4*)&qv[4] = *(const float4*)(rk + d0 + 4);
  float part = 0.f;
#pragma unroll
  for (int c = 0; c < 8; ++c) part = fmaf(rr[c] * kv[c], qv[c], part);
  part += __shfl_xor(part, 1);
  part += __shfl_xor(part, 2);
  part += __shfl_xor(part, 4);
  __shared__ float red[32];
  if ((tid & 7) == 0) red[tid >> 3] = part;
  __syncthreads();
  int h = tid >> 3;
  float bs = red[h];
  float mean = gn[2 * (b * H_ + h)], istd = gn[2 * (b * H_ + h) + 1];

  float yv[8], vv[8], gg[8], lw[8], lb2[8];
  *(float4*)&yv[0] = *(const float4*)(yb + base + d0);
  *(float4*)&yv[4] = *(const float4*)(yb + base + d0 + 4);
  *(float4*)&vv[0] = *(const float4*)(vb + base + d0);
  *(float4*)&vv[4] = *(const float4*)(vb + base + d0 + 4);
  ld_bf8(gb + base + d0, gg);
  *(float4*)&lw[0] = *(const float4*)(lnw + d0);
  *(float4*)&lw[4] = *(const float4*)(lnw + d0 + 4);
  *(float4*)&lb2[0] = *(const float4*)(lnb + d0);
  *(float4*)&lb2[4] = *(const float4*)(lnb + d0 + 4);

  float o[8];
#pragma unroll
  for (int c = 0; c < 8; ++c)
    o[c] = (fmaf(yv[c] - mean, istd * lw[c], lb2[c]) + bs * vv[c]) * gg[c];
  store_bf4(af + base + d0, o[0], o[1], o[2], o[3]);
  store_bf4(af + base + d0 + 4, o[4], o[5], o[6], o[7]);
}

// ---------------- tail: x_last + v_first passthrough ----------------
__global__ __launch_bounds__(256)
void tail_copy(const float* __restrict__ x, const float* __restrict__ vf_in,
               const float* __restrict__ vfin, const int* __restrict__ layer,
               float* __restrict__ oxl, float* __restrict__ ovf)
{
  size_t i4 = (size_t)blockIdx.x * 256 + threadIdx.x;
  size_t e = i4 * 4;
  if (e >= BTD) return;
  int lay = *layer;
  float4 s = (lay == 0) ? *(const float4*)(vfin + e) : *(const float4*)(vf_in + e);
  *(float4*)(ovf + e) = s;
  if (e < (size_t)B_ * D_) {
    size_t b = e >> 11;
    size_t d = e & (D_ - 1);
    *(float4*)(oxl + e) = *(const float4*)(x + (b * T_ + T_ - 1) * (size_t)D_ + d);
  }
}

// ---------------- host launcher ----------------
extern "C" void kernel_launch(void* const* d_in, const int* in_sizes, int n_in,
                              void* d_out, int out_size, void* d_ws, size_t ws_size,
                              hipStream_t stream)
{
  const float* x       = (const float*)d_in[0];
  const float* x_prev  = (const float*)d_in[1];
  const float* v_first = (const float*)d_in[2];
  const float* state0  = (const float*)d_in[3];
  const float* x_r = (const float*)d_in[4];
  const float* x_w = (const float*)d_in[5];
  const float* x_k = (const float*)d_in[6];
  const float* x_v = (const float*)d_in[7];
  const float* x_a = (const float*)d_in[8];
  const float* x_g = (const float*)d_in[9];
  const float* w0 = (const float*)d_in[10];
  const float* w1 = (const float*)d_in[11];
  const float* w2 = (const float*)d_in[12];
  const float* a0 = (const float*)d_in[13];
  const float* a1 = (const float*)d_in[14];
  const float* a2 = (const float*)d_in[15];
  const float* v0 = (const float*)d_in[16];
  const float* v1 = (const float*)d_in[17];
  const float* v2 = (const float*)d_in[18];
  const float* g1 = (const float*)d_in[19];
  const float* g2 = (const float*)d_in[20];
  const float* k_k = (const float*)d_in[21];
  const float* k_a = (const float*)d_in[22];
  const float* r_k = (const float*)d_in[23];
  const float* Rm = (const float*)d_in[24];
  const float* Km = (const float*)d_in[25];
  const float* Vm = (const float*)d_in[26];
  const float* Om = (const float*)d_in[27];
  const float* ln_w = (const float*)d_in[28];
  const float* ln_b = (const float*)d_in[29];
  const int* layer = (const int*)d_in[32];

  float* out        = (float*)d_out;
  float* out_xlast  = out + BTD;
  float* out_state  = out_xlast + (size_t)B_ * D_;
  float* out_vfirst = out_state + (size_t)B_ * H_ * N_ * N_;

  // d_out aliases: ybuf lives in out[] (dead before final GEMM overwrites it);
  // vbuf lives in out_vfirst[] (dead before tail_copy overwrites it).
  float* ybuf = out;
  float* vbuf = out_vfirst;

  char* p = (char*)d_ws;
  auto alloc = [&](size_t bytes) { void* r = p; p += (bytes + 255) & ~(size_t)255; return r; };

  unsigned short* r_bf = (unsigned short*)alloc(BTD * 2);
  unsigned short* k_bf = (unsigned short*)alloc(BTD * 2);
  unsigned short* w_bf = (unsigned short*)alloc(BTD * 2);
  unsigned short* a_bf = (unsigned short*)alloc(BTD * 2);   // a -> aa
  unsigned short* m_bf = (unsigned short*)alloc(BTD * 2);   // v-mix -> bb
  unsigned short* g_bf = (unsigned short*)alloc(BTD * 2);
  unsigned short* xm   = (unsigned short*)alloc(BTD * 2);
  unsigned short* btR  = (unsigned short*)alloc((size_t)D_ * D_ * 2);
  unsigned short* btK  = (unsigned short*)alloc((size_t)D_ * D_ * 2);
  unsigned short* btV  = (unsigned short*)alloc((size_t)D_ * D_ * 2);
  unsigned short* btO  = (unsigned short*)alloc((size_t)D_ * D_ * 2);
  unsigned short* btw1 = (unsigned short*)alloc((size_t)128 * D_ * 2);
  unsigned short* bta1 = (unsigned short*)alloc((size_t)128 * D_ * 2);
  unsigned short* btv1 = (unsigned short*)alloc((size_t)128 * D_ * 2);
  unsigned short* btg1 = (unsigned short*)alloc((size_t)128 * D_ * 2);
  unsigned short* btw2 = (unsigned short*)alloc((size_t)D_ * 64 * 2);
  unsigned short* bta2 = (unsigned short*)alloc((size_t)D_ * 64 * 2);
  unsigned short* btv2 = (unsigned short*)alloc((size_t)D_ * 32 * 2);
  unsigned short* btg2 = (unsigned short*)alloc((size_t)D_ * 128 * 2);
  unsigned short* h1w  = (unsigned short*)alloc((size_t)B_ * T_ * 64 * 2);
  unsigned short* h1a  = (unsigned short*)alloc((size_t)B_ * T_ * 64 * 2);
  unsigned short* h1v  = (unsigned short*)alloc((size_t)B_ * T_ * 32 * 2);
  unsigned short* h1g  = (unsigned short*)alloc((size_t)B_ * T_ * 128 * 2);
  float* gnbuf = (float*)alloc(256 * 4);
  (void)ws_size; (void)in_sizes; (void)n_in; (void)out_size;

  const int MIXG = (int)(BTD / 4 / 256);   // 8192

  // weight transposes (bf16)
  transpose_bf16<<<dim3(32, 32, 4), 256, 0, stream>>>(Rm, Km, Vm, Om, btR, btK, btV, btO, D_, D_, D_);
  transpose_bf16<<<dim3(32, 2, 2), 256, 0, stream>>>(w1, a1, nullptr, nullptr, btw1, bta1, nullptr, nullptr, D_, 64, 128);
  transpose_bf16<<<dim3(32, 2, 1), 256, 0, stream>>>(v1, nullptr, nullptr, nullptr, btv1, nullptr, nullptr, nullptr, D_, 32, 128);
  transpose_bf16<<<dim3(32, 2, 1), 256, 0, stream>>>(g1, nullptr, nullptr, nullptr, btg1, nullptr, nullptr, nullptr, D_, 128, 128);
  transpose_bf16<<<dim3(1, 32, 2), 256, 0, stream>>>(w2, a2, nullptr, nullptr, btw2, bta2, nullptr, nullptr, 64, D_, D_);
  transpose_bf16<<<dim3(1, 32, 1), 256, 0, stream>>>(v2, nullptr, nullptr, nullptr, btv2, nullptr, nullptr, nullptr, 32, D_, D_);
  transpose_bf16<<<dim3(2, 32, 1), 256, 0, stream>>>(g2, nullptr, nullptr, nullptr, btg2, nullptr, nullptr, nullptr, 128, D_, D_);

  // big projections (one shared bf16 A buffer, regenerated per use)
  mix_kernel<<<MIXG, 256, 0, stream>>>(x, x_prev, x_r, xm);
  gemm_bt<3><<<dim3(32, 16), 256, 0, stream>>>(xm, btR, nullptr, r_bf, D_, D_, D_, nullptr);
  mix_kernel<<<MIXG, 256, 0, stream>>>(x, x_prev, x_k, xm);
  gemm_bt<3><<<dim3(32, 16), 256, 0, stream>>>(xm, btK, nullptr, k_bf, D_, D_, D_, nullptr);
  mix_kernel<<<MIXG, 256, 0, stream>>>(x, x_prev, x_v, xm);
  gemm_bt<0><<<dim3(32, 16), 256, 0, stream>>>(xm, btV, vbuf, nullptr, D_, D_, D_, nullptr);
  gemm_bt<3><<<dim3(32, 1), 256, 0, stream>>>(xm, btv1, nullptr, h1v, D_, 32, 32, nullptr);
  mix_kernel<<<MIXG, 256, 0, stream>>>(x, x_prev, x_w, xm);
  gemm_bt<1><<<dim3(32, 1), 256, 0, stream>>>(xm, btw1, nullptr, h1w, D_, 64, 64, nullptr);
  mix_kernel<<<MIXG, 256, 0, stream>>>(x, x_prev, x_a, xm);
  gemm_bt<3><<<dim3(32, 1), 256, 0, stream>>>(xm, bta1, nullptr, h1a, D_, 64, 64, nullptr);
  mix_kernel<<<MIXG, 256, 0, stream>>>(x, x_prev, x_g, xm);
  gemm_bt<2><<<dim3(32, 1), 256, 0, stream>>>(xm, btg1, nullptr, h1g, D_, 128, 128, nullptr);

  // LoRA second stages (bf16 outputs)
  gemm_bt<7><<<dim3(32, 16), 256, 0, stream>>>(h1w, btw2, nullptr, w_bf, 64, D_, D_, w0);
  gemm_bt<6><<<dim3(32, 16), 256, 0, stream>>>(h1a, bta2, nullptr, a_bf, 64, D_, D_, a0);
  gemm_bt<6><<<dim3(32, 16), 256, 0, stream>>>(h1v, btv2, nullptr, m_bf, 32, D_, D_, v0);
  gemm_bt<3><<<dim3(32, 16), 256, 0, stream>>>(h1g, btg2, nullptr, g_bf, 128, D_, D_, nullptr);

  // kk/k/v finalize + aa/bb
  prep_kernel<<<32768, 256, 0, stream>>>(k_bf, a_bf, vbuf, m_bf, v_first, k_k, k_a, layer);

  // sequential scan
  scan_kernel<<<256, 256, 0, stream>>>(r_bf, w_bf, k_bf, vbuf, a_bf, m_bf, state0, ybuf, out_state);

  // group norm + final A + output GEMM
  gn_stats<<<128, 256, 0, stream>>>(ybuf, gnbuf);
  final_mix<<<B_ * T_, 256, 0, stream>>>(ybuf, gnbuf, r_bf, k_bf, vbuf, g_bf, ln_w, ln_b, r_k, xm);
  gemm_bt<0><<<dim3(32, 16), 256, 0, stream>>>(xm, btO, out, nullptr, D_, D_, D_, nullptr);

  // tails (after final GEMM: overwrites the vbuf alias region last)
  tail_copy<<<MIXG, 256, 0, stream>>>(x, v_first, vbuf, layer, out_xlast, out_vfirst);
}

// Round 3
// 1359.389 us; speedup vs baseline: 1.3931x; 1.3931x over previous
//
#include <hip/hip_runtime.h>
#include <math.h>
#include <stdint.h>

// ---------------- constants ----------------
#define B_ 4
#define T_ 1024
#define D_ 2048
#define H_ 32
#define N_ 64
static constexpr size_t BTD = (size_t)B_ * T_ * D_;   // 8388608

typedef __attribute__((ext_vector_type(8))) short short8;
typedef __attribute__((ext_vector_type(4))) float floatx4;

typedef __attribute__((address_space(3))) unsigned int       lds_u32;
typedef __attribute__((address_space(1))) const unsigned int glb_u32;

__device__ __forceinline__ void async_cp16(const unsigned short* g, unsigned short* l) {
  __builtin_amdgcn_global_load_lds((glb_u32*)g, (lds_u32*)l, 16, 0, 0);
}

__device__ __forceinline__ unsigned short f2bf(float f) {
  union { float f; unsigned int u; } v; v.f = f;
  unsigned int r = v.u + 0x7fffu + ((v.u >> 16) & 1u);
  return (unsigned short)(r >> 16);
}

__device__ __forceinline__ float bf2f(unsigned short u) {
  union { unsigned int u; float f; } v; v.u = (unsigned int)u << 16;
  return v.f;
}

__device__ __forceinline__ void store_bf4(unsigned short* dst, float a, float b, float c, float d) {
  unsigned long long v = (unsigned long long)f2bf(a) | ((unsigned long long)f2bf(b) << 16)
                       | ((unsigned long long)f2bf(c) << 32) | ((unsigned long long)f2bf(d) << 48);
  *(unsigned long long*)dst = v;
}

// load 8 bf16 (16B) -> 8 fp32
__device__ __forceinline__ void ld_bf8(const unsigned short* p, float* o) {
  union { short8 v; unsigned short u[8]; } t;
  t.v = *(const short8*)p;
#pragma unroll
  for (int c = 0; c < 8; ++c) o[c] = bf2f(t.u[c]);
}

// 4 bf16 packed in uint2 -> 4 fp32
__device__ __forceinline__ void cv4(uint2 r, float* o) {
  union { unsigned int u; float f; } t;
  t.u = r.x << 16;         o[0] = t.f;
  t.u = r.x & 0xffff0000u; o[1] = t.f;
  t.u = r.y << 16;         o[2] = t.f;
  t.u = r.y & 0xffff0000u; o[3] = t.f;
}

__device__ __forceinline__ float sigm(float z) { return 1.f / (1.f + expf(-z)); }

// ---------------- token-shift mix: out_bf16 = x + (shift(x)-x)*coef ----------------
__global__ __launch_bounds__(256)
void mix_kernel(const float* __restrict__ x, const float* __restrict__ xprev,
                const float* __restrict__ coef, unsigned short* __restrict__ out)
{
  size_t i4 = (size_t)blockIdx.x * 256 + threadIdx.x;
  size_t e = i4 * 4;
  if (e >= BTD) return;
  int d = (int)(e & (D_ - 1));
  size_t bt = e >> 11;          // b*T + t
  int t = (int)(bt & (T_ - 1));
  float4 xv = *(const float4*)(x + e);
  float4 xs;
  if (t == 0) xs = *(const float4*)(xprev + ((bt >> 10) << 11) + d);
  else        xs = *(const float4*)(x + e - D_);
  float4 cf = *(const float4*)(coef + d);
  float o0 = xv.x + (xs.x - xv.x) * cf.x;
  float o1 = xv.y + (xs.y - xv.y) * cf.y;
  float o2 = xv.z + (xs.z - xv.z) * cf.z;
  float o3 = xv.w + (xs.w - xv.w) * cf.w;
  store_bf4(out + e, o0, o1, o2, o3);
}

// ---------------- transpose fp32 [R][C] -> bf16 [Cout][R], zero-pad c>=C ----------------
__global__ __launch_bounds__(256)
void transpose_bf16(const float* sA, const float* sB, const float* sC, const float* sD,
                    unsigned short* dA, unsigned short* dB, unsigned short* dC, unsigned short* dD,
                    int R, int C, int Cout)
{
  const float* src = blockIdx.z == 0 ? sA : blockIdx.z == 1 ? sB : blockIdx.z == 2 ? sC : sD;
  unsigned short* dst = blockIdx.z == 0 ? dA : blockIdx.z == 1 ? dB : blockIdx.z == 2 ? dC : dD;
  __shared__ float tile[64][65];
  int rBase = blockIdx.x * 64;
  int cBase = blockIdx.y * 64;
  int tid = threadIdx.x;
  int tc = tid & 63, tr4 = tid >> 6;
#pragma unroll
  for (int jj = 0; jj < 16; ++jj) {
    int r = rBase + jj * 4 + tr4;
    int c = cBase + tc;
    float v = (r < R && c < C) ? src[(size_t)r * C + c] : 0.f;
    tile[jj * 4 + tr4][tc] = v;
  }
  __syncthreads();
#pragma unroll
  for (int jj = 0; jj < 16; ++jj) {
    int cl = jj * 4 + tr4;
    int rl = tc;
    int c = cBase + cl, r = rBase + rl;
    if (c < Cout && r < R)
      dst[(size_t)c * R + r] = f2bf(tile[rl][cl]);
  }
}

// ---------------- bf16 MFMA GEMM: C[M,N] = A[M,K] @ BT[N,K]^T, fused epilogues ----------------
// EPI 0: fp32 raw              1: bf16 tanh     2: bf16 sigmoid    3: bf16 raw
// EPI 6: bf16 sigmoid(bias+v)  7: bf16 exp(-0.606531*sigmoid(bias+v))
template<int EPI>
__global__ __launch_bounds__(256, 2)
void gemm_bt(const unsigned short* __restrict__ A, const unsigned short* __restrict__ BT,
             float* __restrict__ Cf, unsigned short* __restrict__ Cb,
             int K, int ldc, int Nout, const float* __restrict__ bias)
{
  __shared__ unsigned short lA[128 * 32];
  __shared__ unsigned short lB[128 * 32];
  int tid = threadIdx.x;
  int lane = tid & 63;
  int wv = tid >> 6;
  int wrow = wv >> 1, wcol = wv & 1;
  int mBase = blockIdx.x * 128;
  int nBase = blockIdx.y * 128;
  int r16 = lane & 15, q = lane >> 4;

  floatx4 acc[4][4];
  floatx4 zero = {0.f, 0.f, 0.f, 0.f};
#pragma unroll
  for (int i = 0; i < 4; i++)
#pragma unroll
    for (int j = 0; j < 4; j++) acc[i][j] = zero;

  int arow = tid >> 2, ach = (tid & 3) * 8;
  const unsigned short* ga0 = A  + (size_t)(mBase + arow) * K + ach;
  const unsigned short* ga1 = A  + (size_t)(mBase + 64 + arow) * K + ach;
  const unsigned short* gb0 = BT + (size_t)(nBase + arow) * K + ach;
  const unsigned short* gb1 = BT + (size_t)(nBase + 64 + arow) * K + ach;
  unsigned short* la0 = lA + tid * 8;
  unsigned short* la1 = lA + 2048 + tid * 8;
  unsigned short* lb0 = lB + tid * 8;
  unsigned short* lb1 = lB + 2048 + tid * 8;

  for (int kb = 0; kb < K; kb += 32) {
    async_cp16(ga0 + kb, la0);
    async_cp16(ga1 + kb, la1);
    async_cp16(gb0 + kb, lb0);
    async_cp16(gb1 + kb, lb1);
    __syncthreads();
    short8 af[4], bf[4];
#pragma unroll
    for (int i = 0; i < 4; i++)
      af[i] = *(const short8*)(lA + (wrow * 64 + i * 16 + r16) * 32 + q * 8);
#pragma unroll
    for (int j = 0; j < 4; j++)
      bf[j] = *(const short8*)(lB + (wcol * 64 + j * 16 + r16) * 32 + q * 8);
#pragma unroll
    for (int i = 0; i < 4; i++)
#pragma unroll
      for (int j = 0; j < 4; j++)
        acc[i][j] = __builtin_amdgcn_mfma_f32_16x16x32_bf16(af[i], bf[j], acc[i][j], 0, 0, 0);
    __syncthreads();
  }

#pragma unroll
  for (int i = 0; i < 4; i++) {
    int r0 = mBase + wrow * 64 + i * 16 + q * 4;
#pragma unroll
    for (int j = 0; j < 4; j++) {
      int c = nBase + wcol * 64 + j * 16 + r16;
#pragma unroll
      for (int rg = 0; rg < 4; rg++) {
        float v = acc[i][j][rg];
        size_t idx = (size_t)(r0 + rg) * ldc + c;
        if (EPI == 0) {
          Cf[idx] = v;
        } else if (EPI == 1) {
          if (c < Nout) Cb[idx] = f2bf(tanhf(v));
        } else if (EPI == 2) {
          if (c < Nout) Cb[idx] = f2bf(sigm(v));
        } else if (EPI == 3) {
          if (c < Nout) Cb[idx] = f2bf(v);
        } else if (EPI == 6) {
          Cb[idx] = f2bf(sigm(bias[c] + v));
        } else if (EPI == 7) {
          Cb[idx] = f2bf(expf(-0.606531f * sigm(bias[c] + v)));
        }
      }
    }
  }
}

// ---------------- prep: kk norm, k/v finalize, aa/bb (in place, bf16) ----------------
__global__ __launch_bounds__(256)
void prep_kernel(unsigned short* __restrict__ kb, unsigned short* __restrict__ ab,
                 float* __restrict__ vb, unsigned short* __restrict__ vmb,
                 const float* __restrict__ vfirst, const float* __restrict__ kkc,
                 const float* __restrict__ kac, const int* __restrict__ layer)
{
  int g = blockIdx.x * 4 + (threadIdx.x >> 6);  // (b*T+t)*H + h
  int n = threadIdx.x & 63;
  size_t idx = (size_t)g * 64 + n;
  int d = ((g & (H_ - 1)) << 6) + n;
  float kr = bf2f(kb[idx]);
  float av = bf2f(ab[idx]);
  float vr = vb[idx];
  float vm = bf2f(vmb[idx]);
  float vf = vfirst[idx];
  float kkv = kr * kkc[d];
  float ss = kkv * kkv;
#pragma unroll
  for (int m = 1; m < 64; m <<= 1) ss += __shfl_xor(ss, m);
  float nrm = fmaxf(sqrtf(ss), 1e-12f);
  kkv = kkv / nrm;
  float kf = kr * (1.f + (av - 1.f) * kac[d]);
  float vfin = (*layer == 0) ? vr : vr + (vf - vr) * vm;
  kb[idx] = f2bf(kf);
  vb[idx] = vfin;
  ab[idx] = f2bf(-kkv);          // aa
  vmb[idx] = f2bf(kkv * av);     // bb
}

// ---------------- sequential scan: 4 cols/lane, 16 lanes/row, depth-8 prefetch ring ----------------
__global__ __launch_bounds__(256, 2)
void scan_kernel(const unsigned short* __restrict__ rb, const unsigned short* __restrict__ wb,
                 const unsigned short* __restrict__ kb, const float* __restrict__ vb,
                 const unsigned short* __restrict__ ab, const unsigned short* __restrict__ bbv,
                 const float* __restrict__ s0, float* __restrict__ yb,
                 float* __restrict__ sf)
{
  int blk = blockIdx.x;        // 0..511
  int bh = blk >> 2;           // b*H + h
  int quarter = blk & 3;
  int b = bh >> 5, h = bh & 31;
  int tid = threadIdx.x;
  int lane = tid & 63;
  int wvi = tid >> 6;
  int i = quarter * 16 + wvi * 4 + (lane >> 4);   // state row
  int p = lane & 15;                              // col group (4 cols)
  int co = p * 4;

  float st[4];
  {
    const float* sp = s0 + ((size_t)bh * 64 + i) * 64 + co;
    *(float4*)st = *(const float4*)sp;
  }
  size_t base = (size_t)b * T_ * D_ + h * 64;
  const unsigned short* pr = rb + base + co;
  const unsigned short* pw = wb + base + co;
  const unsigned short* pk = kb + base + co;
  const unsigned short* pa = ab + base + co;
  const unsigned short* pb = bbv + base + co;
  const float* pv = vb + base + i;
  float* py = yb + base + i;

  // prefetch ring, depth 8
  uint2 rgR[8], rgW[8], rgK[8], rgA[8], rgB[8];
  float rgV[8];
#pragma unroll
  for (int s = 0; s < 8; ++s) {
    size_t o = (size_t)s * D_;
    rgR[s] = *(const uint2*)(pr + o);
    rgW[s] = *(const uint2*)(pw + o);
    rgK[s] = *(const uint2*)(pk + o);
    rgA[s] = *(const uint2*)(pa + o);
    rgB[s] = *(const uint2*)(pb + o);
    rgV[s] = pv[o];
  }

  for (int tb = 0; tb < T_; tb += 8) {
#pragma unroll
    for (int s = 0; s < 8; ++s) {
      int t = tb + s;
      size_t o = (size_t)t * D_;
      float av[4], wv4[4], kv[4], bv[4], rv[4];
      cv4(rgA[s], av);
      cv4(rgW[s], wv4);
      cv4(rgK[s], kv);
      cv4(rgB[s], bv);
      cv4(rgR[s], rv);
      float vi = rgV[s];

      // prefetch t+8 into this stage (issued early; consumed 8 iters later)
      int tn = t + 8;
      size_t on = (size_t)(tn < T_ ? tn : 0) * D_;
      rgR[s] = *(const uint2*)(pr + on);
      rgW[s] = *(const uint2*)(pw + on);
      rgK[s] = *(const uint2*)(pk + on);
      rgA[s] = *(const uint2*)(pa + on);
      rgB[s] = *(const uint2*)(pb + on);
      rgV[s] = pv[on];

      float sa = 0.f;
#pragma unroll
      for (int c = 0; c < 4; ++c) sa = fmaf(st[c], av[c], sa);
      sa += __shfl_xor(sa, 1);
      sa += __shfl_xor(sa, 2);
      sa += __shfl_xor(sa, 4);
      sa += __shfl_xor(sa, 8);

#pragma unroll
      for (int c = 0; c < 4; ++c)
        st[c] = fmaf(st[c], wv4[c], fmaf(vi, kv[c], sa * bv[c]));

      float y = 0.f;
#pragma unroll
      for (int c = 0; c < 4; ++c) y = fmaf(st[c], rv[c], y);
      y += __shfl_xor(y, 1);
      y += __shfl_xor(y, 2);
      y += __shfl_xor(y, 4);
      y += __shfl_xor(y, 8);
      if (p == 0) py[o] = y;
    }
  }

  float* sp = sf + ((size_t)bh * 64 + i) * 64 + co;
  *(float4*)sp = *(float4*)st;
}

// ---------------- group-norm stats per (b,h) over (T,N) ----------------
__global__ __launch_bounds__(256)
void gn_stats(const float* __restrict__ yb, float* __restrict__ gn)
{
  int bh = blockIdx.x;
  int b = bh >> 5, h = bh & 31;
  int tid = threadIdx.x;
  int lane = tid & 63, wv = tid >> 6;
  size_t base = (size_t)b * T_ * D_ + h * 64;
  int n = tid & 63, t0 = tid >> 6;
  float s = 0.f, s2 = 0.f;
  for (int t = t0; t < T_; t += 4) {
    float v = yb[base + (size_t)t * D_ + n];
    s += v; s2 += v * v;
  }
#pragma unroll
  for (int m = 1; m < 64; m <<= 1) { s += __shfl_xor(s, m); s2 += __shfl_xor(s2, m); }
  __shared__ float ls[4], ls2[4];
  if (lane == 0) { ls[wv] = s; ls2[wv] = s2; }
  __syncthreads();
  if (tid == 0) {
    float S = ls[0] + ls[1] + ls[2] + ls[3];
    float S2 = ls2[0] + ls2[1] + ls2[2] + ls2[3];
    float mean = S * (1.f / 65536.f);
    float var = S2 * (1.f / 65536.f) - mean * mean;
    gn[2 * bh] = mean;
    gn[2 * bh + 1] = rsqrtf(var + 0.00064f);
  }
}

// ---------------- final A build: ((gn(y) + bonus)*g) -> bf16 ----------------
__global__ __launch_bounds__(256)
void final_mix(const float* __restrict__ yb, const float* __restrict__ gn,
               const unsigned short* __restrict__ rb, const unsigned short* __restrict__ kb,
               const float* __restrict__ vb, const unsigned short* __restrict__ gb,
               const float* __restrict__ lnw, const float* __restrict__ lnb,
               const float* __restrict__ rk, unsigned short* __restrict__ af)
{
  int bt = blockIdx.x;
  int b = bt >> 10;
  size_t base = (size_t)bt * D_;
  int tid = threadIdx.x;
  int d0 = tid * 8;

  float rr[8], kv[8], qv[8];
  ld_bf8(rb + base + d0, rr);
  ld_bf8(kb + base + d0, kv);
  *(float4*)&qv[0] = *(const float4*)(rk + d0);
  *(float4*)&qv[4] = *(const float4*)(rk + d0 + 4);
  float part = 0.f;
#pragma unroll
  for (int c = 0; c < 8; ++c) part = fmaf(rr[c] * kv[c], qv[c], part);
  part += __shfl_xor(part, 1);
  part += __shfl_xor(part, 2);
  part += __shfl_xor(part, 4);
  __shared__ float red[32];
  if ((tid & 7) == 0) red[tid >> 3] = part;
  __syncthreads();
  int h = tid >> 3;
  float bs = red[h];
  float mean = gn[2 * (b * H_ + h)], istd = gn[2 * (b * H_ + h) + 1];

  float yv[8], vv[8], gg[8], lw[8], lb2[8];
  *(float4*)&yv[0] = *(const float4*)(yb + base + d0);
  *(float4*)&yv[4] = *(const float4*)(yb + base + d0 + 4);
  *(float4*)&vv[0] = *(const float4*)(vb + base + d0);
  *(float4*)&vv[4] = *(const float4*)(vb + base + d0 + 4);
  ld_bf8(gb + base + d0, gg);
  *(float4*)&lw[0] = *(const float4*)(lnw + d0);
  *(float4*)&lw[4] = *(const float4*)(lnw + d0 + 4);
  *(float4*)&lb2[0] = *(const float4*)(lnb + d0);
  *(float4*)&lb2[4] = *(const float4*)(lnb + d0 + 4);

  float o[8];
#pragma unroll
  for (int c = 0; c < 8; ++c)
    o[c] = (fmaf(yv[c] - mean, istd * lw[c], lb2[c]) + bs * vv[c]) * gg[c];
  store_bf4(af + base + d0, o[0], o[1], o[2], o[3]);
  store_bf4(af + base + d0 + 4, o[4], o[5], o[6], o[7]);
}

// ---------------- tail: x_last + v_first passthrough ----------------
__global__ __launch_bounds__(256)
void tail_copy(const float* __restrict__ x, const float* __restrict__ vf_in,
               const float* __restrict__ vfin, const int* __restrict__ layer,
               float* __restrict__ oxl, float* __restrict__ ovf)
{
  size_t i4 = (size_t)blockIdx.x * 256 + threadIdx.x;
  size_t e = i4 * 4;
  if (e >= BTD) return;
  int lay = *layer;
  float4 s = (lay == 0) ? *(const float4*)(vfin + e) : *(const float4*)(vf_in + e);
  *(float4*)(ovf + e) = s;
  if (e < (size_t)B_ * D_) {
    size_t b = e >> 11;
    size_t d = e & (D_ - 1);
    *(float4*)(oxl + e) = *(const float4*)(x + (b * T_ + T_ - 1) * (size_t)D_ + d);
  }
}

// ---------------- host launcher ----------------
extern "C" void kernel_launch(void* const* d_in, const int* in_sizes, int n_in,
                              void* d_out, int out_size, void* d_ws, size_t ws_size,
                              hipStream_t stream)
{
  const float* x       = (const float*)d_in[0];
  const float* x_prev  = (const float*)d_in[1];
  const float* v_first = (const float*)d_in[2];
  const float* state0  = (const float*)d_in[3];
  const float* x_r = (const float*)d_in[4];
  const float* x_w = (const float*)d_in[5];
  const float* x_k = (const float*)d_in[6];
  const float* x_v = (const float*)d_in[7];
  const float* x_a = (const float*)d_in[8];
  const float* x_g = (const float*)d_in[9];
  const float* w0 = (const float*)d_in[10];
  const float* w1 = (const float*)d_in[11];
  const float* w2 = (const float*)d_in[12];
  const float* a0 = (const float*)d_in[13];
  const float* a1 = (const float*)d_in[14];
  const float* a2 = (const float*)d_in[15];
  const float* v0 = (const float*)d_in[16];
  const float* v1 = (const float*)d_in[17];
  const float* v2 = (const float*)d_in[18];
  const float* g1 = (const float*)d_in[19];
  const float* g2 = (const float*)d_in[20];
  const float* k_k = (const float*)d_in[21];
  const float* k_a = (const float*)d_in[22];
  const float* r_k = (const float*)d_in[23];
  const float* Rm = (const float*)d_in[24];
  const float* Km = (const float*)d_in[25];
  const float* Vm = (const float*)d_in[26];
  const float* Om = (const float*)d_in[27];
  const float* ln_w = (const float*)d_in[28];
  const float* ln_b = (const float*)d_in[29];
  const int* layer = (const int*)d_in[32];

  float* out        = (float*)d_out;
  float* out_xlast  = out + BTD;
  float* out_state  = out_xlast + (size_t)B_ * D_;
  float* out_vfirst = out_state + (size_t)B_ * H_ * N_ * N_;

  // d_out aliases: ybuf lives in out[] (dead before final GEMM overwrites it);
  // vbuf lives in out_vfirst[] (dead before tail_copy overwrites it).
  float* ybuf = out;
  float* vbuf = out_vfirst;

  char* p = (char*)d_ws;
  auto alloc = [&](size_t bytes) { void* r = p; p += (bytes + 255) & ~(size_t)255; return r; };

  unsigned short* r_bf = (unsigned short*)alloc(BTD * 2);
  unsigned short* k_bf = (unsigned short*)alloc(BTD * 2);
  unsigned short* w_bf = (unsigned short*)alloc(BTD * 2);
  unsigned short* a_bf = (unsigned short*)alloc(BTD * 2);   // a -> aa
  unsigned short* m_bf = (unsigned short*)alloc(BTD * 2);   // v-mix -> bb
  unsigned short* g_bf = (unsigned short*)alloc(BTD * 2);
  unsigned short* xm   = (unsigned short*)alloc(BTD * 2);
  unsigned short* btR  = (unsigned short*)alloc((size_t)D_ * D_ * 2);
  unsigned short* btK  = (unsigned short*)alloc((size_t)D_ * D_ * 2);
  unsigned short* btV  = (unsigned short*)alloc((size_t)D_ * D_ * 2);
  unsigned short* btO  = (unsigned short*)alloc((size_t)D_ * D_ * 2);
  unsigned short* btw1 = (unsigned short*)alloc((size_t)128 * D_ * 2);
  unsigned short* bta1 = (unsigned short*)alloc((size_t)128 * D_ * 2);
  unsigned short* btv1 = (unsigned short*)alloc((size_t)128 * D_ * 2);
  unsigned short* btg1 = (unsigned short*)alloc((size_t)128 * D_ * 2);
  unsigned short* btw2 = (unsigned short*)alloc((size_t)D_ * 64 * 2);
  unsigned short* bta2 = (unsigned short*)alloc((size_t)D_ * 64 * 2);
  unsigned short* btv2 = (unsigned short*)alloc((size_t)D_ * 32 * 2);
  unsigned short* btg2 = (unsigned short*)alloc((size_t)D_ * 128 * 2);
  unsigned short* h1w  = (unsigned short*)alloc((size_t)B_ * T_ * 64 * 2);
  unsigned short* h1a  = (unsigned short*)alloc((size_t)B_ * T_ * 64 * 2);
  unsigned short* h1v  = (unsigned short*)alloc((size_t)B_ * T_ * 32 * 2);
  unsigned short* h1g  = (unsigned short*)alloc((size_t)B_ * T_ * 128 * 2);
  float* gnbuf = (float*)alloc(256 * 4);
  (void)ws_size; (void)in_sizes; (void)n_in; (void)out_size;

  const int MIXG = (int)(BTD / 4 / 256);   // 8192

  // weight transposes (bf16)
  transpose_bf16<<<dim3(32, 32, 4), 256, 0, stream>>>(Rm, Km, Vm, Om, btR, btK, btV, btO, D_, D_, D_);
  transpose_bf16<<<dim3(32, 2, 2), 256, 0, stream>>>(w1, a1, nullptr, nullptr, btw1, bta1, nullptr, nullptr, D_, 64, 128);
  transpose_bf16<<<dim3(32, 2, 1), 256, 0, stream>>>(v1, nullptr, nullptr, nullptr, btv1, nullptr, nullptr, nullptr, D_, 32, 128);
  transpose_bf16<<<dim3(32, 2, 1), 256, 0, stream>>>(g1, nullptr, nullptr, nullptr, btg1, nullptr, nullptr, nullptr, D_, 128, 128);
  transpose_bf16<<<dim3(1, 32, 2), 256, 0, stream>>>(w2, a2, nullptr, nullptr, btw2, bta2, nullptr, nullptr, 64, D_, D_);
  transpose_bf16<<<dim3(1, 32, 1), 256, 0, stream>>>(v2, nullptr, nullptr, nullptr, btv2, nullptr, nullptr, nullptr, 32, D_, D_);
  transpose_bf16<<<dim3(2, 32, 1), 256, 0, stream>>>(g2, nullptr, nullptr, nullptr, btg2, nullptr, nullptr, nullptr, 128, D_, D_);

  // big projections (one shared bf16 A buffer, regenerated per use)
  mix_kernel<<<MIXG, 256, 0, stream>>>(x, x_prev, x_r, xm);
  gemm_bt<3><<<dim3(32, 16), 256, 0, stream>>>(xm, btR, nullptr, r_bf, D_, D_, D_, nullptr);
  mix_kernel<<<MIXG, 256, 0, stream>>>(x, x_prev, x_k, xm);
  gemm_bt<3><<<dim3(32, 16), 256, 0, stream>>>(xm, btK, nullptr, k_bf, D_, D_, D_, nullptr);
  mix_kernel<<<MIXG, 256, 0, stream>>>(x, x_prev, x_v, xm);
  gemm_bt<0><<<dim3(32, 16), 256, 0, stream>>>(xm, btV, vbuf, nullptr, D_, D_, D_, nullptr);
  gemm_bt<3><<<dim3(32, 1), 256, 0, stream>>>(xm, btv1, nullptr, h1v, D_, 32, 32, nullptr);
  mix_kernel<<<MIXG, 256, 0, stream>>>(x, x_prev, x_w, xm);
  gemm_bt<1><<<dim3(32, 1), 256, 0, stream>>>(xm, btw1, nullptr, h1w, D_, 64, 64, nullptr);
  mix_kernel<<<MIXG, 256, 0, stream>>>(x, x_prev, x_a, xm);
  gemm_bt<3><<<dim3(32, 1), 256, 0, stream>>>(xm, bta1, nullptr, h1a, D_, 64, 64, nullptr);
  mix_kernel<<<MIXG, 256, 0, stream>>>(x, x_prev, x_g, xm);
  gemm_bt<2><<<dim3(32, 1), 256, 0, stream>>>(xm, btg1, nullptr, h1g, D_, 128, 128, nullptr);

  // LoRA second stages (bf16 outputs)
  gemm_bt<7><<<dim3(32, 16), 256, 0, stream>>>(h1w, btw2, nullptr, w_bf, 64, D_, D_, w0);
  gemm_bt<6><<<dim3(32, 16), 256, 0, stream>>>(h1a, bta2, nullptr, a_bf, 64, D_, D_, a0);
  gemm_bt<6><<<dim3(32, 16), 256, 0, stream>>>(h1v, btv2, nullptr, m_bf, 32, D_, D_, v0);
  gemm_bt<3><<<dim3(32, 16), 256, 0, stream>>>(h1g, btg2, nullptr, g_bf, 128, D_, D_, nullptr);

  // kk/k/v finalize + aa/bb
  prep_kernel<<<32768, 256, 0, stream>>>(k_bf, a_bf, vbuf, m_bf, v_first, k_k, k_a, layer);

  // sequential scan (4 cols/lane, depth-8 prefetch, 2 waves/SIMD)
  scan_kernel<<<512, 256, 0, stream>>>(r_bf, w_bf, k_bf, vbuf, a_bf, m_bf, state0, ybuf, out_state);

  // group norm + final A + output GEMM
  gn_stats<<<128, 256, 0, stream>>>(ybuf, gnbuf);
  final_mix<<<B_ * T_, 256, 0, stream>>>(ybuf, gnbuf, r_bf, k_bf, vbuf, g_bf, ln_w, ln_b, r_k, xm);
  gemm_bt<0><<<dim3(32, 16), 256, 0, stream>>>(xm, btO, out, nullptr, D_, D_, D_, nullptr);

  // tails (after final GEMM: overwrites the vbuf alias region last)
  tail_copy<<<MIXG, 256, 0, stream>>>(x, v_first, vbuf, layer, out_xlast, out_vfirst);
}

// Round 4
// 1269.400 us; speedup vs baseline: 1.4919x; 1.0709x over previous
//
#include <hip/hip_runtime.h>
#include <math.h>
#include <stdint.h>

// ---------------- constants ----------------
#define B_ 4
#define T_ 1024
#define D_ 2048
#define H_ 32
#define N_ 64
static constexpr size_t BTD = (size_t)B_ * T_ * D_;   // 8388608

typedef __attribute__((ext_vector_type(8))) short short8;
typedef __attribute__((ext_vector_type(4))) float floatx4;

typedef __attribute__((address_space(3))) unsigned int       lds_u32;
typedef __attribute__((address_space(1))) const unsigned int glb_u32;

__device__ __forceinline__ void async_cp16(const unsigned short* g, unsigned short* l) {
  __builtin_amdgcn_global_load_lds((glb_u32*)g, (lds_u32*)l, 16, 0, 0);
}

__device__ __forceinline__ unsigned short f2bf(float f) {
  union { float f; unsigned int u; } v; v.f = f;
  unsigned int r = v.u + 0x7fffu + ((v.u >> 16) & 1u);
  return (unsigned short)(r >> 16);
}

__device__ __forceinline__ float bf2f(unsigned short u) {
  union { unsigned int u; float f; } v; v.u = (unsigned int)u << 16;
  return v.f;
}

__device__ __forceinline__ void store_bf4(unsigned short* dst, float a, float b, float c, float d) {
  unsigned long long v = (unsigned long long)f2bf(a) | ((unsigned long long)f2bf(b) << 16)
                       | ((unsigned long long)f2bf(c) << 32) | ((unsigned long long)f2bf(d) << 48);
  *(unsigned long long*)dst = v;
}

// load 8 bf16 (16B) -> 8 fp32
__device__ __forceinline__ void ld_bf8(const unsigned short* p, float* o) {
  union { short8 v; unsigned short u[8]; } t;
  t.v = *(const short8*)p;
#pragma unroll
  for (int c = 0; c < 8; ++c) o[c] = bf2f(t.u[c]);
}

// 2 bf16 packed in uint -> 2 fp32
__device__ __forceinline__ void cv2(unsigned int r, float* o) {
  union { unsigned int u; float f; } t;
  t.u = r << 16;         o[0] = t.f;
  t.u = r & 0xffff0000u; o[1] = t.f;
}

__device__ __forceinline__ float sigm(float z) { return 1.f / (1.f + expf(-z)); }

// ---------------- fused token-shift mix x3: o_i = bf16(x + (shift(x)-x)*c_i) ----------------
__global__ __launch_bounds__(256)
void mix3_kernel(const float* __restrict__ x, const float* __restrict__ xprev,
                 const float* __restrict__ c0, const float* __restrict__ c1,
                 const float* __restrict__ c2,
                 unsigned short* __restrict__ o0, unsigned short* __restrict__ o1,
                 unsigned short* __restrict__ o2)
{
  size_t e = ((size_t)blockIdx.x * 256 + threadIdx.x) * 4;
  if (e >= BTD) return;
  int d = (int)(e & (D_ - 1));
  size_t bt = e >> 11;
  int t = (int)(bt & (T_ - 1));
  float4 xv = *(const float4*)(x + e);
  float4 xs;
  if (t == 0) xs = *(const float4*)(xprev + ((bt >> 10) << 11) + d);
  else        xs = *(const float4*)(x + e - D_);
  float dx0 = xs.x - xv.x, dx1 = xs.y - xv.y, dx2 = xs.z - xv.z, dx3 = xs.w - xv.w;

  float4 cf;
  cf = *(const float4*)(c0 + d);
  store_bf4(o0 + e, xv.x + dx0 * cf.x, xv.y + dx1 * cf.y, xv.z + dx2 * cf.z, xv.w + dx3 * cf.w);
  cf = *(const float4*)(c1 + d);
  store_bf4(o1 + e, xv.x + dx0 * cf.x, xv.y + dx1 * cf.y, xv.z + dx2 * cf.z, xv.w + dx3 * cf.w);
  cf = *(const float4*)(c2 + d);
  store_bf4(o2 + e, xv.x + dx0 * cf.x, xv.y + dx1 * cf.y, xv.z + dx2 * cf.z, xv.w + dx3 * cf.w);
}

// ---------------- transpose fp32 [R][C] -> bf16 [Cout][Rout], zero-pad ----------------
__global__ __launch_bounds__(256)
void transpose_bf16(const float* sA, const float* sB, const float* sC, const float* sD,
                    unsigned short* dA, unsigned short* dB, unsigned short* dC, unsigned short* dD,
                    int R, int C, int Cout, int Rout)
{
  const float* src = blockIdx.z == 0 ? sA : blockIdx.z == 1 ? sB : blockIdx.z == 2 ? sC : sD;
  unsigned short* dst = blockIdx.z == 0 ? dA : blockIdx.z == 1 ? dB : blockIdx.z == 2 ? dC : dD;
  __shared__ float tile[64][65];
  int rBase = blockIdx.x * 64;
  int cBase = blockIdx.y * 64;
  int tid = threadIdx.x;
  int tc = tid & 63, tr4 = tid >> 6;
#pragma unroll
  for (int jj = 0; jj < 16; ++jj) {
    int r = rBase + jj * 4 + tr4;
    int c = cBase + tc;
    float v = (r < R && c < C) ? src[(size_t)r * C + c] : 0.f;
    tile[jj * 4 + tr4][tc] = v;
  }
  __syncthreads();
#pragma unroll
  for (int jj = 0; jj < 16; ++jj) {
    int cl = jj * 4 + tr4;
    int rl = tc;
    int c = cBase + cl, r = rBase + rl;
    if (c < Cout && r < Rout)
      dst[(size_t)c * Rout + r] = f2bf(tile[rl][cl]);
  }
}

// ---------------- shared MFMA GEMM core: acc = A[M,K] @ BT[N,K]^T (128x128 tile) ----------------
__device__ __forceinline__ void gemm_core(const unsigned short* __restrict__ A,
                                          const unsigned short* __restrict__ BT,
                                          int K, unsigned short* lA, unsigned short* lB,
                                          floatx4 (&acc)[4][4])
{
  int tid = threadIdx.x;
  int lane = tid & 63;
  int wv = tid >> 6;
  int wrow = wv >> 1, wcol = wv & 1;
  int mBase = blockIdx.x * 128;
  int nBase = blockIdx.y * 128;
  int r16 = lane & 15, q = lane >> 4;

  floatx4 zero = {0.f, 0.f, 0.f, 0.f};
#pragma unroll
  for (int i = 0; i < 4; i++)
#pragma unroll
    for (int j = 0; j < 4; j++) acc[i][j] = zero;

  int arow = tid >> 2, ach = (tid & 3) * 8;
  const unsigned short* ga0 = A  + (size_t)(mBase + arow) * K + ach;
  const unsigned short* ga1 = A  + (size_t)(mBase + 64 + arow) * K + ach;
  const unsigned short* gb0 = BT + (size_t)(nBase + arow) * K + ach;
  const unsigned short* gb1 = BT + (size_t)(nBase + 64 + arow) * K + ach;
  unsigned short* la0 = lA + tid * 8;
  unsigned short* la1 = lA + 2048 + tid * 8;
  unsigned short* lb0 = lB + tid * 8;
  unsigned short* lb1 = lB + 2048 + tid * 8;

  for (int kb = 0; kb < K; kb += 32) {
    async_cp16(ga0 + kb, la0);
    async_cp16(ga1 + kb, la1);
    async_cp16(gb0 + kb, lb0);
    async_cp16(gb1 + kb, lb1);
    __syncthreads();
    short8 af[4], bf[4];
#pragma unroll
    for (int i = 0; i < 4; i++)
      af[i] = *(const short8*)(lA + (wrow * 64 + i * 16 + r16) * 32 + q * 8);
#pragma unroll
    for (int j = 0; j < 4; j++)
      bf[j] = *(const short8*)(lB + (wcol * 64 + j * 16 + r16) * 32 + q * 8);
#pragma unroll
    for (int i = 0; i < 4; i++)
#pragma unroll
      for (int j = 0; j < 4; j++)
        acc[i][j] = __builtin_amdgcn_mfma_f32_16x16x32_bf16(af[i], bf[j], acc[i][j], 0, 0, 0);
    __syncthreads();
  }
}

// epilogue index helper: row r0+rg, col c
#define GEMM_EPILOGUE_HEAD                                        \
  int tid = threadIdx.x;                                          \
  int lane = tid & 63;                                            \
  int wv = tid >> 6;                                              \
  int wrow = wv >> 1, wcol = wv & 1;                              \
  int mBase = blockIdx.x * 128;                                   \
  int nBase = blockIdx.y * 128;                                   \
  int r16 = lane & 15, q = lane >> 4;                             \
  (void)lane;

// ---------------- generic single GEMM (templated epilogue) ----------------
// EPI 0: fp32 raw   3: bf16 raw (zero-pad c>=Nout)
template<int EPI>
__global__ __launch_bounds__(256, 2)
void gemm_bt(const unsigned short* __restrict__ A, const unsigned short* __restrict__ BT,
             float* __restrict__ Cf, unsigned short* __restrict__ Cb,
             int K, int ldc, int Nout)
{
  __shared__ unsigned short lA[128 * 32];
  __shared__ unsigned short lB[128 * 32];
  floatx4 acc[4][4];
  gemm_core(A, BT, K, lA, lB, acc);
  GEMM_EPILOGUE_HEAD
#pragma unroll
  for (int i = 0; i < 4; i++) {
    int r0 = mBase + wrow * 64 + i * 16 + q * 4;
#pragma unroll
    for (int j = 0; j < 4; j++) {
      int c = nBase + wcol * 64 + j * 16 + r16;
#pragma unroll
      for (int rg = 0; rg < 4; rg++) {
        float v = acc[i][j][rg];
        size_t idx = (size_t)(r0 + rg) * ldc + c;
        if (EPI == 0) Cf[idx] = v;
        else          Cb[idx] = f2bf(c < Nout ? v : 0.f);
      }
    }
  }
}

// ---------------- batched R/K/V projections (z = 0,1,2) ----------------
__global__ __launch_bounds__(256, 2)
void gemm_rkv(const unsigned short* __restrict__ xr, const unsigned short* __restrict__ xk,
              const unsigned short* __restrict__ xv,
              const unsigned short* __restrict__ btR, const unsigned short* __restrict__ btK,
              const unsigned short* __restrict__ btV,
              unsigned short* __restrict__ r_bf, unsigned short* __restrict__ k_bf,
              float* __restrict__ vbuf)
{
  __shared__ unsigned short lA[128 * 32];
  __shared__ unsigned short lB[128 * 32];
  int z = blockIdx.z;
  const unsigned short* A  = z == 0 ? xr  : z == 1 ? xk  : xv;
  const unsigned short* BT = z == 0 ? btR : z == 1 ? btK : btV;
  floatx4 acc[4][4];
  gemm_core(A, BT, D_, lA, lB, acc);
  GEMM_EPILOGUE_HEAD
  unsigned short* db = z == 0 ? r_bf : k_bf;
#pragma unroll
  for (int i = 0; i < 4; i++) {
    int r0 = mBase + wrow * 64 + i * 16 + q * 4;
#pragma unroll
    for (int j = 0; j < 4; j++) {
      int c = nBase + wcol * 64 + j * 16 + r16;
#pragma unroll
      for (int rg = 0; rg < 4; rg++) {
        float v = acc[i][j][rg];
        size_t idx = (size_t)(r0 + rg) * D_ + c;
        if (z == 2) vbuf[idx] = v;
        else        db[idx] = f2bf(v);
      }
    }
  }
}

// ---------------- batched LoRA stage-1 (w:tanh, a:raw, g:sigm), N=128, zero-padded ----------------
__global__ __launch_bounds__(256, 2)
void gemm_lora1(const unsigned short* __restrict__ xw, const unsigned short* __restrict__ xa,
                const unsigned short* __restrict__ xg,
                const unsigned short* __restrict__ btw1, const unsigned short* __restrict__ bta1,
                const unsigned short* __restrict__ btg1,
                unsigned short* __restrict__ h1w, unsigned short* __restrict__ h1a,
                unsigned short* __restrict__ h1g)
{
  __shared__ unsigned short lA[128 * 32];
  __shared__ unsigned short lB[128 * 32];
  int z = blockIdx.z;
  const unsigned short* A  = z == 0 ? xw   : z == 1 ? xa   : xg;
  const unsigned short* BT = z == 0 ? btw1 : z == 1 ? bta1 : btg1;
  unsigned short* dst      = z == 0 ? h1w  : z == 1 ? h1a  : h1g;
  int Nout = z == 2 ? 128 : 64;
  floatx4 acc[4][4];
  gemm_core(A, BT, D_, lA, lB, acc);
  GEMM_EPILOGUE_HEAD
#pragma unroll
  for (int i = 0; i < 4; i++) {
    int r0 = mBase + wrow * 64 + i * 16 + q * 4;
#pragma unroll
    for (int j = 0; j < 4; j++) {
      int c = nBase + wcol * 64 + j * 16 + r16;
#pragma unroll
      for (int rg = 0; rg < 4; rg++) {
        float v = acc[i][j][rg];
        if (z == 0) v = tanhf(v);
        else if (z == 2) v = sigm(v);
        size_t idx = (size_t)(r0 + rg) * 128 + c;
        dst[idx] = f2bf(c < Nout ? v : 0.f);
      }
    }
  }
}

// ---------------- batched LoRA stage-2 (K=128 padded) ----------------
// z0: w = exp(-0.606531*sigm(w0+v))  z1: a = sigm(a0+v)  z2: vmix = sigm(v0+v)  z3: g raw
__global__ __launch_bounds__(256, 2)
void gemm_lora2(const unsigned short* __restrict__ h1w, const unsigned short* __restrict__ h1a,
                const unsigned short* __restrict__ h1v, const unsigned short* __restrict__ h1g,
                const unsigned short* __restrict__ btw2, const unsigned short* __restrict__ bta2,
                const unsigned short* __restrict__ btv2, const unsigned short* __restrict__ btg2,
                unsigned short* __restrict__ w_bf, unsigned short* __restrict__ a_bf,
                unsigned short* __restrict__ m_bf, unsigned short* __restrict__ g_bf,
                const float* __restrict__ w0, const float* __restrict__ a0,
                const float* __restrict__ v0)
{
  __shared__ unsigned short lA[128 * 32];
  __shared__ unsigned short lB[128 * 32];
  int z = blockIdx.z;
  const unsigned short* A  = z == 0 ? h1w  : z == 1 ? h1a  : z == 2 ? h1v  : h1g;
  const unsigned short* BT = z == 0 ? btw2 : z == 1 ? bta2 : z == 2 ? btv2 : btg2;
  unsigned short* dst      = z == 0 ? w_bf : z == 1 ? a_bf : z == 2 ? m_bf : g_bf;
  const float* bias        = z == 0 ? w0   : z == 1 ? a0   : z == 2 ? v0   : nullptr;
  floatx4 acc[4][4];
  gemm_core(A, BT, 128, lA, lB, acc);
  GEMM_EPILOGUE_HEAD
#pragma unroll
  for (int i = 0; i < 4; i++) {
    int r0 = mBase + wrow * 64 + i * 16 + q * 4;
#pragma unroll
    for (int j = 0; j < 4; j++) {
      int c = nBase + wcol * 64 + j * 16 + r16;
#pragma unroll
      for (int rg = 0; rg < 4; rg++) {
        float v = acc[i][j][rg];
        if (z == 0)      v = expf(-0.606531f * sigm(bias[c] + v));
        else if (z < 3)  v = sigm(bias[c] + v);
        size_t idx = (size_t)(r0 + rg) * D_ + c;
        dst[idx] = f2bf(v);
      }
    }
  }
}

// ---------------- prep: kk norm, k/v finalize, aa/bb (in place, bf16) ----------------
__global__ __launch_bounds__(256)
void prep_kernel(unsigned short* __restrict__ kb, unsigned short* __restrict__ ab,
                 float* __restrict__ vb, unsigned short* __restrict__ vmb,
                 const float* __restrict__ vfirst, const float* __restrict__ kkc,
                 const float* __restrict__ kac, const int* __restrict__ layer)
{
  int g = blockIdx.x * 4 + (threadIdx.x >> 6);  // (b*T+t)*H + h
  int n = threadIdx.x & 63;
  size_t idx = (size_t)g * 64 + n;
  int d = ((g & (H_ - 1)) << 6) + n;
  float kr = bf2f(kb[idx]);
  float av = bf2f(ab[idx]);
  float vr = vb[idx];
  float vm = bf2f(vmb[idx]);
  float vf = vfirst[idx];
  float kkv = kr * kkc[d];
  float ss = kkv * kkv;
#pragma unroll
  for (int m = 1; m < 64; m <<= 1) ss += __shfl_xor(ss, m);
  float nrm = fmaxf(sqrtf(ss), 1e-12f);
  kkv = kkv / nrm;
  float kf = kr * (1.f + (av - 1.f) * kac[d]);
  float vfin = (*layer == 0) ? vr : vr + (vf - vr) * vm;
  kb[idx] = f2bf(kf);
  vb[idx] = vfin;
  ab[idx] = f2bf(-kkv);          // aa
  vmb[idx] = f2bf(kkv * av);     // bb
}

// ---------------- sequential scan: 2 cols/lane, 32 lanes/row, depth-8 prefetch ring ----------------
__global__ __launch_bounds__(256, 4)
void scan_kernel(const unsigned short* __restrict__ rb, const unsigned short* __restrict__ wb,
                 const unsigned short* __restrict__ kb, const float* __restrict__ vb,
                 const unsigned short* __restrict__ ab, const unsigned short* __restrict__ bbv,
                 const float* __restrict__ s0, float* __restrict__ yb,
                 float* __restrict__ sf)
{
  int blk = blockIdx.x;        // 0..1023
  int bh = blk >> 3;           // b*H + h (0..127)
  int oct = blk & 7;
  int b = bh >> 5, h = bh & 31;
  int tid = threadIdx.x;
  int lane = tid & 63;
  int wvi = tid >> 6;
  int i = oct * 8 + wvi * 2 + (lane >> 5);   // state row (0..63)
  int p = lane & 31;                          // col pair index
  int co = p * 2;

  float st[2];
  {
    const float* sp = s0 + ((size_t)bh * 64 + i) * 64 + co;
    float2 s2 = *(const float2*)sp;
    st[0] = s2.x; st[1] = s2.y;
  }
  size_t base = (size_t)b * T_ * D_ + h * 64;
  const unsigned short* pr = rb + base + co;
  const unsigned short* pw = wb + base + co;
  const unsigned short* pk = kb + base + co;
  const unsigned short* pa = ab + base + co;
  const unsigned short* pb = bbv + base + co;
  const float* pv = vb + base + i;
  float* py = yb + base + i;

  // prefetch ring, depth 8
  unsigned int rgR[8], rgW[8], rgK[8], rgA[8], rgB[8];
  float rgV[8];
#pragma unroll
  for (int s = 0; s < 8; ++s) {
    size_t o = (size_t)s * D_;
    rgR[s] = *(const unsigned int*)(pr + o);
    rgW[s] = *(const unsigned int*)(pw + o);
    rgK[s] = *(const unsigned int*)(pk + o);
    rgA[s] = *(const unsigned int*)(pa + o);
    rgB[s] = *(const unsigned int*)(pb + o);
    rgV[s] = pv[o];
  }

  for (int tb = 0; tb < T_; tb += 8) {
#pragma unroll
    for (int s = 0; s < 8; ++s) {
      int t = tb + s;
      size_t o = (size_t)t * D_;
      float av[2], wv2[2], kv[2], bv[2], rv[2];
      cv2(rgA[s], av);
      cv2(rgW[s], wv2);
      cv2(rgK[s], kv);
      cv2(rgB[s], bv);
      cv2(rgR[s], rv);
      float vi = rgV[s];

      // prefetch t+8 into this stage
      int tn = t + 8;
      size_t on = (size_t)(tn < T_ ? tn : 0) * D_;
      rgR[s] = *(const unsigned int*)(pr + on);
      rgW[s] = *(const unsigned int*)(pw + on);
      rgK[s] = *(const unsigned int*)(pk + on);
      rgA[s] = *(const unsigned int*)(pa + on);
      rgB[s] = *(const unsigned int*)(pb + on);
      rgV[s] = pv[on];

      float sa = fmaf(st[0], av[0], st[1] * av[1]);
      sa += __shfl_xor(sa, 1);
      sa += __shfl_xor(sa, 2);
      sa += __shfl_xor(sa, 4);
      sa += __shfl_xor(sa, 8);
      sa += __shfl_xor(sa, 16);

      st[0] = fmaf(st[0], wv2[0], fmaf(vi, kv[0], sa * bv[0]));
      st[1] = fmaf(st[1], wv2[1], fmaf(vi, kv[1], sa * bv[1]));

      float y = fmaf(st[0], rv[0], st[1] * rv[1]);
      y += __shfl_xor(y, 1);
      y += __shfl_xor(y, 2);
      y += __shfl_xor(y, 4);
      y += __shfl_xor(y, 8);
      y += __shfl_xor(y, 16);
      if (p == 0) py[o] = y;
    }
  }

  float* sp = sf + ((size_t)bh * 64 + i) * 64 + co;
  *(float2*)sp = make_float2(st[0], st[1]);
}

// ---------------- group-norm stats per (b,h) over (T,N) ----------------
__global__ __launch_bounds__(256)
void gn_stats(const float* __restrict__ yb, float* __restrict__ gn)
{
  int bh = blockIdx.x;
  int b = bh >> 5, h = bh & 31;
  int tid = threadIdx.x;
  int lane = tid & 63, wv = tid >> 6;
  size_t base = (size_t)b * T_ * D_ + h * 64;
  int n = tid & 63, t0 = tid >> 6;
  float s = 0.f, s2 = 0.f;
  for (int t = t0; t < T_; t += 4) {
    float v = yb[base + (size_t)t * D_ + n];
    s += v; s2 += v * v;
  }
#pragma unroll
  for (int m = 1; m < 64; m <<= 1) { s += __shfl_xor(s, m); s2 += __shfl_xor(s2, m); }
  __shared__ float ls[4], ls2[4];
  if (lane == 0) { ls[wv] = s; ls2[wv] = s2; }
  __syncthreads();
  if (tid == 0) {
    float S = ls[0] + ls[1] + ls[2] + ls[3];
    float S2 = ls2[0] + ls2[1] + ls2[2] + ls2[3];
    float mean = S * (1.f / 65536.f);
    float var = S2 * (1.f / 65536.f) - mean * mean;
    gn[2 * bh] = mean;
    gn[2 * bh + 1] = rsqrtf(var + 0.00064f);
  }
}

// ---------------- final A build: ((gn(y) + bonus)*g) -> bf16 ----------------
__global__ __launch_bounds__(256)
void final_mix(const float* __restrict__ yb, const float* __restrict__ gn,
               const unsigned short* __restrict__ rb, const unsigned short* __restrict__ kb,
               const float* __restrict__ vb, const unsigned short* __restrict__ gb,
               const float* __restrict__ lnw, const float* __restrict__ lnb,
               const float* __restrict__ rk, unsigned short* __restrict__ af)
{
  int bt = blockIdx.x;
  int b = bt >> 10;
  size_t base = (size_t)bt * D_;
  int tid = threadIdx.x;
  int d0 = tid * 8;

  float rr[8], kv[8], qv[8];
  ld_bf8(rb + base + d0, rr);
  ld_bf8(kb + base + d0, kv);
  *(float4*)&qv[0] = *(const float4*)(rk + d0);
  *(float4*)&qv[4] = *(const float4*)(rk + d0 + 4);
  float part = 0.f;
#pragma unroll
  for (int c = 0; c < 8; ++c) part = fmaf(rr[c] * kv[c], qv[c], part);
  part += __shfl_xor(part, 1);
  part += __shfl_xor(part, 2);
  part += __shfl_xor(part, 4);
  __shared__ float red[32];
  if ((tid & 7) == 0) red[tid >> 3] = part;
  __syncthreads();
  int h = tid >> 3;
  float bs = red[h];
  float mean = gn[2 * (b * H_ + h)], istd = gn[2 * (b * H_ + h) + 1];

  float yv[8], vv[8], gg[8], lw[8], lb2[8];
  *(float4*)&yv[0] = *(const float4*)(yb + base + d0);
  *(float4*)&yv[4] = *(const float4*)(yb + base + d0 + 4);
  *(float4*)&vv[0] = *(const float4*)(vb + base + d0);
  *(float4*)&vv[4] = *(const float4*)(vb + base + d0 + 4);
  ld_bf8(gb + base + d0, gg);
  *(float4*)&lw[0] = *(const float4*)(lnw + d0);
  *(float4*)&lw[4] = *(const float4*)(lnw + d0 + 4);
  *(float4*)&lb2[0] = *(const float4*)(lnb + d0);
  *(float4*)&lb2[4] = *(const float4*)(lnb + d0 + 4);

  float o[8];
#pragma unroll
  for (int c = 0; c < 8; ++c)
    o[c] = (fmaf(yv[c] - mean, istd * lw[c], lb2[c]) + bs * vv[c]) * gg[c];
  store_bf4(af + base + d0, o[0], o[1], o[2], o[3]);
  store_bf4(af + base + d0 + 4, o[4], o[5], o[6], o[7]);
}

// ---------------- tail: x_last + v_first passthrough ----------------
__global__ __launch_bounds__(256)
void tail_copy(const float* __restrict__ x, const float* __restrict__ vf_in,
               const float* __restrict__ vfin, const int* __restrict__ layer,
               float* __restrict__ oxl, float* __restrict__ ovf)
{
  size_t e = ((size_t)blockIdx.x * 256 + threadIdx.x) * 4;
  if (e >= BTD) return;
  int lay = *layer;
  float4 s = (lay == 0) ? *(const float4*)(vfin + e) : *(const float4*)(vf_in + e);
  *(float4*)(ovf + e) = s;
  if (e < (size_t)B_ * D_) {
    size_t b = e >> 11;
    size_t d = e & (D_ - 1);
    *(float4*)(oxl + e) = *(const float4*)(x + (b * T_ + T_ - 1) * (size_t)D_ + d);
  }
}

// ---------------- host launcher ----------------
extern "C" void kernel_launch(void* const* d_in, const int* in_sizes, int n_in,
                              void* d_out, int out_size, void* d_ws, size_t ws_size,
                              hipStream_t stream)
{
  const float* x       = (const float*)d_in[0];
  const float* x_prev  = (const float*)d_in[1];
  const float* v_first = (const float*)d_in[2];
  const float* state0  = (const float*)d_in[3];
  const float* x_r = (const float*)d_in[4];
  const float* x_w = (const float*)d_in[5];
  const float* x_k = (const float*)d_in[6];
  const float* x_v = (const float*)d_in[7];
  const float* x_a = (const float*)d_in[8];
  const float* x_g = (const float*)d_in[9];
  const float* w0 = (const float*)d_in[10];
  const float* w1 = (const float*)d_in[11];
  const float* w2 = (const float*)d_in[12];
  const float* a0 = (const float*)d_in[13];
  const float* a1 = (const float*)d_in[14];
  const float* a2 = (const float*)d_in[15];
  const float* v0 = (const float*)d_in[16];
  const float* v1 = (const float*)d_in[17];
  const float* v2 = (const float*)d_in[18];
  const float* g1 = (const float*)d_in[19];
  const float* g2 = (const float*)d_in[20];
  const float* k_k = (const float*)d_in[21];
  const float* k_a = (const float*)d_in[22];
  const float* r_k = (const float*)d_in[23];
  const float* Rm = (const float*)d_in[24];
  const float* Km = (const float*)d_in[25];
  const float* Vm = (const float*)d_in[26];
  const float* Om = (const float*)d_in[27];
  const float* ln_w = (const float*)d_in[28];
  const float* ln_b = (const float*)d_in[29];
  const int* layer = (const int*)d_in[32];

  float* out        = (float*)d_out;
  float* out_xlast  = out + BTD;
  float* out_state  = out_xlast + (size_t)B_ * D_;
  float* out_vfirst = out_state + (size_t)B_ * H_ * N_ * N_;

  // d_out aliases (stream-serialized lifetimes):
  float* ybuf = out;          // dead before final O-GEMM writes out
  float* vbuf = out_vfirst;   // dead before tail_copy writes v_first out

  char* p = (char*)d_ws;
  auto alloc = [&](size_t bytes) { void* r = p; p += (bytes + 255) & ~(size_t)255; return r; };

  unsigned short* mix0 = (unsigned short*)alloc(BTD * 2);  // xr / xw / final A
  unsigned short* mix1 = (unsigned short*)alloc(BTD * 2);  // xk / xa ; then w_bf
  unsigned short* mix2 = (unsigned short*)alloc(BTD * 2);  // xv / xg ; then a_bf (aa)
  unsigned short* r_bf = (unsigned short*)alloc(BTD * 2);
  unsigned short* k_bf = (unsigned short*)alloc(BTD * 2);
  unsigned short* m_bf = (unsigned short*)alloc(BTD * 2);  // vmix -> bb
  unsigned short* g_bf = (unsigned short*)alloc(BTD * 2);
  unsigned short* w_bf = mix1;
  unsigned short* a_bf = mix2;
  unsigned short* btR  = (unsigned short*)alloc((size_t)D_ * D_ * 2);
  unsigned short* btK  = (unsigned short*)alloc((size_t)D_ * D_ * 2);
  unsigned short* btV  = (unsigned short*)alloc((size_t)D_ * D_ * 2);
  unsigned short* btO  = (unsigned short*)alloc((size_t)D_ * D_ * 2);
  unsigned short* btw1 = (unsigned short*)alloc((size_t)128 * D_ * 2);
  unsigned short* bta1 = (unsigned short*)alloc((size_t)128 * D_ * 2);
  unsigned short* btv1 = (unsigned short*)alloc((size_t)128 * D_ * 2);
  unsigned short* btg1 = (unsigned short*)alloc((size_t)128 * D_ * 2);
  unsigned short* btw2 = (unsigned short*)alloc((size_t)D_ * 128 * 2);
  unsigned short* bta2 = (unsigned short*)alloc((size_t)D_ * 128 * 2);
  unsigned short* btv2 = (unsigned short*)alloc((size_t)D_ * 128 * 2);
  unsigned short* btg2 = (unsigned short*)alloc((size_t)D_ * 128 * 2);
  unsigned short* h1w  = (unsigned short*)alloc((size_t)B_ * T_ * 128 * 2);
  unsigned short* h1a  = (unsigned short*)alloc((size_t)B_ * T_ * 128 * 2);
  unsigned short* h1v  = (unsigned short*)alloc((size_t)B_ * T_ * 128 * 2);
  unsigned short* h1g  = (unsigned short*)alloc((size_t)B_ * T_ * 128 * 2);
  float* gnbuf = (float*)alloc(256 * 4);
  (void)ws_size; (void)in_sizes; (void)n_in; (void)out_size;

  const int MIXG = (int)(BTD / 4 / 256);   // 8192

  // weight transposes (bf16, zero-padded)
  transpose_bf16<<<dim3(32, 32, 4), 256, 0, stream>>>(Rm, Km, Vm, Om, btR, btK, btV, btO, D_, D_, D_, D_);
  transpose_bf16<<<dim3(32, 2, 2), 256, 0, stream>>>(w1, a1, nullptr, nullptr, btw1, bta1, nullptr, nullptr, D_, 64, 128, D_);
  transpose_bf16<<<dim3(32, 2, 1), 256, 0, stream>>>(v1, nullptr, nullptr, nullptr, btv1, nullptr, nullptr, nullptr, D_, 32, 128, D_);
  transpose_bf16<<<dim3(32, 2, 1), 256, 0, stream>>>(g1, nullptr, nullptr, nullptr, btg1, nullptr, nullptr, nullptr, D_, 128, 128, D_);
  transpose_bf16<<<dim3(2, 32, 2), 256, 0, stream>>>(w2, a2, nullptr, nullptr, btw2, bta2, nullptr, nullptr, 64, D_, D_, 128);
  transpose_bf16<<<dim3(2, 32, 1), 256, 0, stream>>>(v2, nullptr, nullptr, nullptr, btv2, nullptr, nullptr, nullptr, 32, D_, D_, 128);
  transpose_bf16<<<dim3(2, 32, 1), 256, 0, stream>>>(g2, nullptr, nullptr, nullptr, btg2, nullptr, nullptr, nullptr, 128, D_, D_, 128);

  // phase A: r/k/v mixes -> batched R/K/V GEMMs + v-LoRA1
  mix3_kernel<<<MIXG, 256, 0, stream>>>(x, x_prev, x_r, x_k, x_v, mix0, mix1, mix2);
  gemm_rkv<<<dim3(32, 16, 3), 256, 0, stream>>>(mix0, mix1, mix2, btR, btK, btV, r_bf, k_bf, vbuf);
  gemm_bt<3><<<dim3(32, 1), 256, 0, stream>>>(mix2, btv1, nullptr, h1v, D_, 128, 32);

  // phase B: w/a/g mixes (reuse buffers) -> batched LoRA1 + batched LoRA2
  mix3_kernel<<<MIXG, 256, 0, stream>>>(x, x_prev, x_w, x_a, x_g, mix0, mix1, mix2);
  gemm_lora1<<<dim3(32, 1, 3), 256, 0, stream>>>(mix0, mix1, mix2, btw1, bta1, btg1, h1w, h1a, h1g);
  gemm_lora2<<<dim3(32, 16, 4), 256, 0, stream>>>(h1w, h1a, h1v, h1g, btw2, bta2, btv2, btg2,
                                                  w_bf, a_bf, m_bf, g_bf, w0, a0, v0);

  // kk/k/v finalize + aa/bb
  prep_kernel<<<32768, 256, 0, stream>>>(k_bf, a_bf, vbuf, m_bf, v_first, k_k, k_a, layer);

  // sequential scan (2 cols/lane, depth-8 prefetch, 4 waves/SIMD)
  scan_kernel<<<1024, 256, 0, stream>>>(r_bf, w_bf, k_bf, vbuf, a_bf, m_bf, state0, ybuf, out_state);

  // group norm + final A + output GEMM
  gn_stats<<<128, 256, 0, stream>>>(ybuf, gnbuf);
  final_mix<<<B_ * T_, 256, 0, stream>>>(ybuf, gnbuf, r_bf, k_bf, vbuf, g_bf, ln_w, ln_b, r_k, mix0);
  gemm_bt<0><<<dim3(32, 16), 256, 0, stream>>>(mix0, btO, out, nullptr, D_, D_, D_);

  // tails
  tail_copy<<<MIXG, 256, 0, stream>>>(x, v_first, vbuf, layer, out_xlast, out_vfirst);
}